// Round 7
// baseline (170.383 us; speedup 1.0000x reference)
//
#include <hip/hip_runtime.h>
#include <hip/hip_bf16.h>

#define NTOK 16384
#define NB 16
#define NC 256
#define NK 64
#define EPSF 1e-9f

typedef __attribute__((ext_vector_type(8))) short bf16x8;   // 8 bf16 (4 VGPRs)
typedef __attribute__((ext_vector_type(4))) float f32x4;    // MFMA C/D

__device__ inline unsigned short f2b(float f) {  // RNE f32 -> bf16 bits via HW cvt
  __hip_bfloat16 h = __float2bfloat16(f);
  return *(unsigned short*)&h;
}
__device__ inline float b2f(unsigned short u) {
  union { unsigned u; float f; } v; v.u = ((unsigned)u) << 16; return v.f;
}

// ---------------- Kernel A: weight fusion + Srow zero (unchanged) ----------------
__global__ __launch_bounds__(256) void kA(const float* __restrict__ conv1_w,
                                          const float* __restrict__ conv1_b,
                                          const float* __restrict__ w0,
                                          const float* __restrict__ w1,
                                          const float* __restrict__ b2,
                                          unsigned short* __restrict__ WeffB,
                                          unsigned short* __restrict__ w1Bb,
                                          float* __restrict__ beff,
                                          float* __restrict__ cb,
                                          float* __restrict__ Srow) {
  int blk = blockIdx.x;
  int tid = threadIdx.x;
  if (blk < NK) {
    int k = blk;
    float acc = 0.f;
#pragma unroll 8
    for (int d = 0; d < NC; ++d)
      acc = fmaf(w0[k * NC + d], conv1_w[d * NC + tid], acc);
    WeffB[k * NC + tid] = f2b(acc);
    if (tid == 0) {
      float s = 0.f;
#pragma unroll 8
      for (int d = 0; d < NC; ++d) s = fmaf(w0[k * NC + d], conv1_b[d], s);
      beff[k] = s;
    }
  } else {
    int c = tid;
    float s = 0.f;
#pragma unroll 8
    for (int k = 0; k < NK; ++k) {
      float v = w1[c * NK + k];
      s += v;
      w1Bb[c * NK + k] = f2b(v);
    }
    cb[c] = b2[0] * s;
    for (int i = tid; i < NB * NK; i += 256) Srow[i] = 0.f;
  }
}

// ---------------- Kernel B: round-6 proven version (unchanged) ----------------
__global__ __launch_bounds__(256) void kB(const float* __restrict__ x,
                                          const unsigned short* __restrict__ WeffB,
                                          const float* __restrict__ beff,
                                          unsigned short* __restrict__ ezg,
                                          float* __restrict__ Srow) {
  const int b = blockIdx.y;
  const int tid = threadIdx.x;
  const int lane = tid & 63;
  const int w = tid >> 6;
  const int l15 = lane & 15;
  const int g = lane >> 4;
  const int n0 = blockIdx.x * 128 + w * 32;

  const float* xb = x + (((size_t)b * NC) << 14) + n0 + 2 * l15;

  f32x4 acc[4][2];
#pragma unroll
  for (int kf = 0; kf < 4; ++kf)
#pragma unroll
    for (int nf = 0; nf < 2; ++nf)
      acc[kf][nf] = (f32x4){0.f, 0.f, 0.f, 0.f};

  float2 xp[8];
#pragma unroll
  for (int e = 0; e < 8; ++e)
    xp[e] = *(const float2*)(xb + (((size_t)(g * 8 + e)) << 14));

#pragma unroll
  for (int s = 0; s < 8; ++s) {
    const int c0 = s * 32;
    bf16x8 a[4];
#pragma unroll
    for (int kf = 0; kf < 4; ++kf)
      a[kf] = *(const bf16x8*)(WeffB + ((kf * 16 + l15) << 8) + c0 + g * 8);

    float2 xn[8];
    if (s < 7) {
#pragma unroll
      for (int e = 0; e < 8; ++e)
        xn[e] = *(const float2*)(xb + (((size_t)(c0 + 32 + g * 8 + e)) << 14));
    }

    bf16x8 b0, b1;
#pragma unroll
    for (int e = 0; e < 8; ++e) {
      b0[e] = (short)f2b(xp[e].x);
      b1[e] = (short)f2b(xp[e].y);
    }

#pragma unroll
    for (int kf = 0; kf < 4; ++kf) {
      acc[kf][0] = __builtin_amdgcn_mfma_f32_16x16x32_bf16(a[kf], b0, acc[kf][0], 0, 0, 0);
      acc[kf][1] = __builtin_amdgcn_mfma_f32_16x16x32_bf16(a[kf], b1, acc[kf][1], 0, 0, 0);
    }

    if (s < 7) {
#pragma unroll
      for (int e = 0; e < 8; ++e) xp[e] = xn[e];
    }
  }

  __shared__ float sred[4][NK];
  float rs[16];
#pragma unroll
  for (int kf = 0; kf < 4; ++kf) {
#pragma unroll
    for (int j = 0; j < 4; ++j) {
      const int k = kf * 16 + g * 4 + j;
      const float bv = beff[k];
      float e0 = __expf(acc[kf][0][j] + bv);
      float e1 = __expf(acc[kf][1][j] + bv);
      unsigned pk = (unsigned)f2b(e0) | ((unsigned)f2b(e1) << 16);
      *(unsigned*)(ezg + (((size_t)(b * NK + k)) << 14) + n0 + 2 * l15) = pk;
      rs[kf * 4 + j] = e0 + e1;
    }
  }
#pragma unroll
  for (int m = 1; m < 16; m <<= 1) {
#pragma unroll
    for (int i = 0; i < 16; ++i)
      rs[i] += __shfl_xor(rs[i], m, 64);
  }
  if (l15 == 0) {
#pragma unroll
    for (int i = 0; i < 16; ++i)
      sred[w][(i >> 2) * 16 + g * 4 + (i & 3)] = rs[i];
  }
  __syncthreads();
  if (tid < NK)
    atomicAdd(&Srow[b * NK + tid],
              sred[0][tid] + sred[1][tid] + sred[2][tid] + sred[3][tid]);
}

// ---------------- Kernel C: per-token colsum -> scv[b][n] ----------------
// scv[b][n] = w2[0] / (EPS + sum_k ez[b][k][n]*invS[k]), k ascending (same
// order as the old kCD phase-2, so values are bitwise identical).
// Each thread: 8 consecutive tokens; per-wave reads 1KB contiguous per k-step.
__global__ __launch_bounds__(256) void kC(const unsigned short* __restrict__ ezg,
                                          const float* __restrict__ Srow,
                                          const float* __restrict__ w2,
                                          float* __restrict__ scv) {
  const int b = blockIdx.y;
  const int tid = threadIdx.x;
  __shared__ float invS[NK];
  if (tid < NK) invS[tid] = 1.f / Srow[b * NK + tid];
  __syncthreads();

  const int n0 = (blockIdx.x * 256 + tid) * 8;   // 8 tokens per thread
  const unsigned short* ep = ezg + (((size_t)b * NK) << 14) + n0;
  float s[8];
#pragma unroll
  for (int e = 0; e < 8; ++e) s[e] = 0.f;
#pragma unroll
  for (int k = 0; k < NK; ++k) {
    bf16x8 v = *(const bf16x8*)(ep + (((size_t)k) << 14));
    const float iv = invS[k];
#pragma unroll
    for (int e = 0; e < 8; ++e)
      s[e] += b2f((unsigned short)v[e]) * iv;
  }
  const float w2v = w2[0];
  float4 o0, o1;
  o0.x = w2v / (EPSF + s[0]); o0.y = w2v / (EPSF + s[1]);
  o0.z = w2v / (EPSF + s[2]); o0.w = w2v / (EPSF + s[3]);
  o1.x = w2v / (EPSF + s[4]); o1.y = w2v / (EPSF + s[5]);
  o1.z = w2v / (EPSF + s[6]); o1.w = w2v / (EPSF + s[7]);
  float* op = scv + (((size_t)b) << 14) + n0;
  *(float4*)op = o0;
  *(float4*)(op + 4) = o1;
}

// ---------------- Kernel D: contiguous-out GEMM ----------------
// Block (M, b) owns out rows m = M*256..+255, which need exactly ez k-row M:
// q[r][j] = ez[b][M][r*64+j] * invS[M] * scv[r*64+j]  (invS[M] block-scalar).
// Stage: one contiguous 32KB ez read, prescale, bf16 into XOR-swizzled LDS
// (byte ^= (row&7)<<4). GEMM identical MFMA structure/order to round-3.
// out writes: 256KB fully contiguous per block.
__global__ __launch_bounds__(256) void kD(const unsigned short* __restrict__ ezg,
                                          const float* __restrict__ Srow,
                                          const float* __restrict__ scv,
                                          const unsigned short* __restrict__ w1Bb,
                                          const float* __restrict__ cb,
                                          float* __restrict__ out) {
  const int M = blockIdx.x;
  const int b = blockIdx.y;
  const int tid = threadIdx.x;
  const int lane = tid & 63, wv = tid >> 6, l15 = lane & 15, g = lane >> 4;

  __shared__ unsigned short q[256 * 64];   // 32 KB, row stride 128B, swizzled

  const float invSM = 1.f / Srow[b * NK + M];

  // stage: 2048 16B-chunks; thread handles chunk idx = p*256+tid (8 tokens)
  const unsigned short* ep = ezg + (((size_t)(b * NK + M)) << 14);
  const float* sp = scv + (((size_t)b) << 14);
#pragma unroll
  for (int p = 0; p < 8; ++p) {
    const int idx = p * 256 + tid;
    const int flat = idx * 8;               // first token of chunk
    bf16x8 v = *(const bf16x8*)(ep + flat);
    float4 s0 = *(const float4*)(sp + flat);
    float4 s1 = *(const float4*)(sp + flat + 4);
    bf16x8 o;
    o[0] = (short)f2b(b2f((unsigned short)v[0]) * invSM * s0.x);
    o[1] = (short)f2b(b2f((unsigned short)v[1]) * invSM * s0.y);
    o[2] = (short)f2b(b2f((unsigned short)v[2]) * invSM * s0.z);
    o[3] = (short)f2b(b2f((unsigned short)v[3]) * invSM * s0.w);
    o[4] = (short)f2b(b2f((unsigned short)v[4]) * invSM * s1.x);
    o[5] = (short)f2b(b2f((unsigned short)v[5]) * invSM * s1.y);
    o[6] = (short)f2b(b2f((unsigned short)v[6]) * invSM * s1.z);
    o[7] = (short)f2b(b2f((unsigned short)v[7]) * invSM * s1.w);
    const int r = idx >> 3;                 // out-row within block (0..255)
    const int jb = (idx & 7) * 16;          // byte offset of j-chunk in row
    *(bf16x8*)((char*)q + r * 128 + (jb ^ ((r & 7) << 4))) = o;
  }
  __syncthreads();

  // GEMM: out[M*256+row][c] = sum_j q[row][j]*w1[c][j], 4 c-tiles
#pragma unroll 1
  for (int ct = 0; ct < 4; ++ct) {
    const int c0 = ct * 64;
    bf16x8 bfr[4][2];
#pragma unroll
    for (int cc = 0; cc < 4; ++cc)
#pragma unroll
      for (int kh = 0; kh < 2; ++kh)
        bfr[cc][kh] = *(const bf16x8*)(w1Bb + (c0 + cc * 16 + l15) * NK + kh * 32 + g * 8);

    f32x4 acc[4][4];
#pragma unroll
    for (int mi = 0; mi < 4; ++mi)
#pragma unroll
      for (int cc = 0; cc < 4; ++cc)
        acc[mi][cc] = (f32x4){0.f, 0.f, 0.f, 0.f};

#pragma unroll
    for (int mi = 0; mi < 4; ++mi) {
      const int row = wv * 64 + mi * 16 + l15;
      const int swz = (row & 7) << 4;
      bf16x8 a0 = *(const bf16x8*)((const char*)q + row * 128 + ((g * 16) ^ swz));       // j = g*8..+7
      bf16x8 a1 = *(const bf16x8*)((const char*)q + row * 128 + ((64 + g * 16) ^ swz));  // j = 32+g*8..+7
#pragma unroll
      for (int cc = 0; cc < 4; ++cc) {
        acc[mi][cc] = __builtin_amdgcn_mfma_f32_16x16x32_bf16(a0, bfr[cc][0], acc[mi][cc], 0, 0, 0);
        acc[mi][cc] = __builtin_amdgcn_mfma_f32_16x16x32_bf16(a1, bfr[cc][1], acc[mi][cc], 0, 0, 0);
      }
    }

    // epilogue: out[b][M*256 + row][c] = acc + cb[c]  (contiguous 256KB/block)
#pragma unroll
    for (int mi = 0; mi < 4; ++mi) {
#pragma unroll
      for (int j = 0; j < 4; ++j) {
        const int row = wv * 64 + mi * 16 + g * 4 + j;
        float* op = out + ((size_t)b * NTOK + (size_t)M * 256 + row) * NC;
#pragma unroll
        for (int cc = 0; cc < 4; ++cc) {
          const int c = c0 + cc * 16 + l15;
          op[c] = acc[mi][cc][j] + cb[c];
        }
      }
    }
  }
}

extern "C" void kernel_launch(void* const* d_in, const int* in_sizes, int n_in,
                              void* d_out, int out_size, void* d_ws, size_t ws_size,
                              hipStream_t stream) {
  const float* x       = (const float*)d_in[0];
  const float* conv1_w = (const float*)d_in[1];
  const float* conv1_b = (const float*)d_in[2];
  const float* w0      = (const float*)d_in[3];
  const float* w2      = (const float*)d_in[4];
  const float* b2      = (const float*)d_in[5];
  const float* w1      = (const float*)d_in[6];
  float* out = (float*)d_out;

  unsigned short* ezg = (unsigned short*)d_ws;                 // 16*64*16384 bf16
  float* beff = (float*)(ezg + (size_t)NB * NK * NTOK);        // 64
  float* cb   = beff + NK;                                     // 256
  float* Srow = cb + NC;                                       // 1024
  unsigned short* WeffB = (unsigned short*)(Srow + NB * NK);   // 64*256 bf16
  unsigned short* w1Bb  = WeffB + NK * NC;                     // 256*64 bf16
  float* scv = (float*)(w1Bb + NC * NK);                       // 16*16384 f32 (1 MB)

  hipLaunchKernelGGL(kA, dim3(65), dim3(256), 0, stream,
                     conv1_w, conv1_b, w0, w1, b2, WeffB, w1Bb, beff, cb, Srow);
  hipLaunchKernelGGL(kB, dim3(128, NB), dim3(256), 0, stream, x, WeffB, beff, ezg, Srow);
  hipLaunchKernelGGL(kC, dim3(8, NB), dim3(256), 0, stream, ezg, Srow, w2, scv);
  hipLaunchKernelGGL(kD, dim3(64, NB), dim3(256), 0, stream, ezg, Srow, scv, w1Bb, cb, out);
}